// Round 6
// baseline (393.571 us; speedup 1.0000x reference)
//
#include <hip/hip_runtime.h>
#include <hip/hip_bf16.h>

typedef unsigned short u16;
typedef unsigned int u32;
typedef short bf16x4 __attribute__((ext_vector_type(4)));
typedef short bf16x8 __attribute__((ext_vector_type(8)));
typedef float f32x4 __attribute__((ext_vector_type(4)));
typedef u32 u32x2 __attribute__((ext_vector_type(2)));
typedef u32 u32x4 __attribute__((ext_vector_type(4)));

#define DEVINL __device__ __forceinline__

DEVINL u16 f2bf(float f) {
    u32 u = __builtin_bit_cast(u32, f);
    u32 r = u + 0x7fffu + ((u >> 16) & 1u);   // RNE
    return (u16)(r >> 16);
}

// RNE pack via scalar casts — compiler fuses to v_cvt_pk_bf16_f32 (m240)
DEVINL u32 pack2(float a, float b) {
    u16 lo = __builtin_bit_cast(u16, __float2bfloat16(a));
    u16 hi = __builtin_bit_cast(u16, __float2bfloat16(b));
    return (u32)lo | ((u32)hi << 16);
}

// ---------------------------------------------------------------- cast x -> bf16
__global__ __launch_bounds__(256) void cast_x_kernel(const float4* __restrict__ in,
                                                     u16* __restrict__ outp) {
    int i = blockIdx.x * 256 + threadIdx.x;
    float4 v = in[i];
    ushort4 o;
    o.x = f2bf(v.x); o.y = f2bf(v.y); o.z = f2bf(v.z); o.w = f2bf(v.w);
    *(ushort4*)&outp[(size_t)i * 4] = o;
}

// ------------------------------------------ transpose+cast weights: W[K][N] -> Wt[N][K] bf16
__global__ __launch_bounds__(256) void transpose_cast(
    const float* __restrict__ W0, const float* __restrict__ W1,
    const float* __restrict__ W2, const float* __restrict__ W3,
    u16* __restrict__ T0, u16* __restrict__ T1,
    u16* __restrict__ T2, u16* __restrict__ T3) {
    __shared__ __align__(16) u16 lds[64 * 68];
    int bid = blockIdx.x;
    const float* W; u16* T;
    switch (bid >> 8) {
        case 0:  W = W0; T = T0; break;
        case 1:  W = W1; T = T1; break;
        case 2:  W = W2; T = T2; break;
        default: W = W3; T = T3; break;
    }
    int tile = bid & 255;
    int k0 = (tile >> 4) << 6;
    int n0 = (tile & 15) << 6;
    int t = threadIdx.x;
    int rk = t >> 2;
    int cb = (t & 3) << 4;
#pragma unroll
    for (int j = 0; j < 4; ++j) {
        float4 v = *(const float4*)&W[(size_t)(k0 + rk) * 1024 + n0 + cb + 4 * j];
        ushort4 o;
        o.x = f2bf(v.x); o.y = f2bf(v.y); o.z = f2bf(v.z); o.w = f2bf(v.w);
        *(ushort4*)&lds[rk * 68 + cb + 4 * j] = o;
    }
    __syncthreads();
    int rn = t >> 2;
#pragma unroll
    for (int j2 = 0; j2 < 2; ++j2) {
        u16 tmp[8];
#pragma unroll
        for (int u = 0; u < 8; ++u)
            tmp[u] = lds[(cb + 8 * j2 + u) * 68 + rn];
        *(uint4*)&T[(size_t)(n0 + rn) * 1024 + k0 + cb + 8 * j2] = *(uint4*)tmp;
    }
}

// ---------------------------------------------------------------- GEMM (m97-style 128^2 tile)
// MODE 0: C[4096,3072] = xb @ [Wq|Wk|Wv]^T-stored, +bias; Q (pre-scaled 1/8), K -> [B,H,S,64];
//         V -> [B,H,64,S'] key-PERMUTED transposed (pos = 32kb+8g+j <-> key = 32kb+(j<4?4g+j:16+4g+j-4))
// MODE 1: C[4096,1024] = Ob @ Wo^T-stored, +bo, write fp32 d_out
template <int MODE>
__global__ __launch_bounds__(256) void gemm_kernel(
    const u16* __restrict__ A,
    const u16* __restrict__ W0t, const u16* __restrict__ W1t, const u16* __restrict__ W2t,
    const float* __restrict__ b0, const float* __restrict__ b1, const float* __restrict__ b2,
    u16* __restrict__ Oq, u16* __restrict__ Ok, u16* __restrict__ Ov,
    float* __restrict__ Fout) {
    constexpr int NB = (MODE == 0) ? 24 : 8;
    const int mb = blockIdx.x / NB, nb = blockIdx.x % NB;
    const int m0 = mb * 128, n0 = nb * 128;
    const int tid = threadIdx.x, lane = tid & 63, w = tid >> 6;
    const int wr = w >> 1, wc = w & 1;
    const int c = lane & 15, g = lane >> 4;

    __shared__ __align__(16) u16 Alds[128 * 64];
    __shared__ __align__(16) u16 Blds[128 * 64];

    const u16* Wt; const float* bias; int ncol0;
    if (MODE == 0) {
        const int tsel = n0 >> 10;
        Wt   = (tsel == 0) ? W0t : ((tsel == 1) ? W1t : W2t);
        bias = (tsel == 0) ? b0  : ((tsel == 1) ? b1  : b2);
        ncol0 = n0 & 1023;
    } else {
        Wt = W0t; bias = b0; ncol0 = n0;
    }

    const u16* Asrc = A  + (size_t)(m0    + 32 * w + (lane >> 3)) * 1024 + (lane & 7) * 8;
    const u16* Bsrc = Wt + (size_t)(ncol0 + 32 * w + (lane >> 3)) * 1024 + (lane & 7) * 8;
    u16* AldsW = &Alds[(32 * w) * 64];
    u16* BldsW = &Blds[(32 * w) * 64];

    f32x4 acc[4][4] = {};

    for (int kt = 0; kt < 16; ++kt) {
        const int k0 = kt * 64;
#pragma unroll
        for (int i = 0; i < 4; ++i) {
            __builtin_amdgcn_global_load_lds(
                (const __attribute__((address_space(1))) void*)(Asrc + k0 + i * 8 * 1024),
                (__attribute__((address_space(3))) void*)(AldsW + i * 8 * 64), 16, 0, 0);
            __builtin_amdgcn_global_load_lds(
                (const __attribute__((address_space(1))) void*)(Bsrc + k0 + i * 8 * 1024),
                (__attribute__((address_space(3))) void*)(BldsW + i * 8 * 64), 16, 0, 0);
        }
        __syncthreads();
#pragma unroll
        for (int kk = 0; kk < 2; ++kk) {
            bf16x8 af[4], bfr[4];
#pragma unroll
            for (int mf = 0; mf < 4; ++mf)
                af[mf] = *(const bf16x8*)&Alds[(c + 16 * mf + 64 * wr) * 64 + 8 * g + 32 * kk];
#pragma unroll
            for (int nf = 0; nf < 4; ++nf)
                bfr[nf] = *(const bf16x8*)&Blds[(c + 16 * nf + 64 * wc) * 64 + 8 * g + 32 * kk];
#pragma unroll
            for (int mf = 0; mf < 4; ++mf)
#pragma unroll
                for (int nf = 0; nf < 4; ++nf)
                    acc[mf][nf] = __builtin_amdgcn_mfma_f32_16x16x32_bf16(
                        af[mf], bfr[nf], acc[mf][nf], 0, 0, 0);
        }
        __syncthreads();
    }

    float biasv[4];
#pragma unroll
    for (int nf = 0; nf < 4; ++nf) biasv[nf] = bias[ncol0 + 64 * wc + 16 * nf + c];

    if (MODE == 0) {
        const int bi = m0 >> 11;
        const int tsel = n0 >> 10;
        if (tsel < 2) {
            u16* Odst = (tsel == 0) ? Oq : Ok;
            const float sc = (tsel == 0) ? 0.125f : 1.0f;   // fold 1/sqrt(Dk) into Q
#pragma unroll
            for (int nf = 0; nf < 4; ++nf) {
                const int n_in = ncol0 + 64 * wc + 16 * nf + c;
                const int h = n_in >> 6, d = n_in & 63;
                u16* base = Odst + ((size_t)(bi * 16 + h)) * 2048 * 64 + d;
#pragma unroll
                for (int mf = 0; mf < 4; ++mf)
#pragma unroll
                    for (int r = 0; r < 4; ++r) {
                        const int m = m0 + 64 * wr + 16 * mf + 4 * g + r;
                        const int s = m & 2047;
                        base[(size_t)s * 64] = f2bf((acc[mf][nf][r] + biasv[nf]) * sc);
                    }
            }
        } else {
            // V transposed + key-permuted within each 64-key tile:
            // block of 4 keys s..s+3 (s%4==0) stored at pos = (s&~63) + 32*kb + sub
            //   kb = (s>>5)&1, r5 = s&31, sub = (r5<16) ? 2*r5 : 2*(r5-16)+4
#pragma unroll
            for (int nf = 0; nf < 4; ++nf) {
                const int n_in = ncol0 + 64 * wc + 16 * nf + c;
                const int h = n_in >> 6, d = n_in & 63;
                u16* base = Ov + ((size_t)((bi * 16 + h) * 64 + d)) * 2048;
#pragma unroll
                for (int mf = 0; mf < 4; ++mf) {
                    const int s = (m0 & 2047) + 64 * wr + 16 * mf + 4 * g;
                    const int r5 = s & 31;
                    const int pos = (s & ~63) + 32 * ((s >> 5) & 1)
                                  + ((r5 < 16) ? (2 * r5) : (2 * (r5 - 16) + 4));
                    u32x2 pr = {pack2(acc[mf][nf][0] + biasv[nf], acc[mf][nf][1] + biasv[nf]),
                                pack2(acc[mf][nf][2] + biasv[nf], acc[mf][nf][3] + biasv[nf])};
                    *(u32x2*)&base[pos] = pr;
                }
            }
        }
    } else {
#pragma unroll
        for (int mf = 0; mf < 4; ++mf)
#pragma unroll
            for (int r = 0; r < 4; ++r) {
                const int m = m0 + 64 * wr + 16 * mf + 4 * g + r;
                float* rowp = Fout + (size_t)m * 1024 + n0 + 64 * wc;
#pragma unroll
                for (int nf = 0; nf < 4; ++nf)
                    rowp[16 * nf + c] = acc[mf][nf][r] + biasv[nf];
            }
    }
}

// ---------------------------------------------------------------- flash attention (no-LDS)
// Swapped-operand 16x16x32 (layouts HW-verified in-problem, round 4). K/V are L2-resident
// (512 KB/head); fragments read DIRECTLY from global — no LDS, no barriers, no bank
// conflicts, waves fully independent.
// grid: 1024 = B(2) x H(16) x (2048/64); 4 waves/block; each wave owns 16 q rows.
// Per 64-key tile:
//   S[key][q] via A=K,B=Q (8 MFMA); lane (c,g) holds S[16T+4g+r][q=c].
//   PV claimed k-map kappa(g,j) = 32kb + (j<4 ? 4g+j : 16+4g+j-4); V is stored
//   key-permuted so each A-frag is ONE contiguous 16B load; B-frag = lane's own
//   packed P words (zero shuffles).
__global__ __launch_bounds__(256) void attn_kernel(
    const u16* __restrict__ Q, const u16* __restrict__ K, const u16* __restrict__ Vp,
    u16* __restrict__ O) {
    const int bid0 = blockIdx.x;
    const int bid = (bid0 & 7) * 128 + (bid0 >> 3);   // XCD-chunked swizzle (1024 % 8 == 0)
    const int qb = bid & 31, h = (bid >> 5) & 15, b = bid >> 9;
    const int tid = threadIdx.x, lane = tid & 63, w = tid >> 6;
    const int c = lane & 15, g = lane >> 4;

    const size_t hoff = ((size_t)(b * 16 + h)) * 2048 * 64;
    const u16* Qh = Q + hoff;
    const u16* Kh = K + hoff;
    const u16* Vh = Vp + hoff;      // [64 dims][2048 key-positions (permuted per 64)]

    const int q = qb * 64 + w * 16 + c;   // this lane's q-row
    bf16x8 qf[2];
#pragma unroll
    for (int kk = 0; kk < 2; ++kk)
        qf[kk] = *(const bf16x8*)&Qh[(size_t)q * 64 + 8 * g + 32 * kk];

    // per-lane fragment base pointers
    const u16* pK = Kh + (size_t)c * 64 + 8 * g;     // + kt*4096 + T*1024 + 32*kk
    const u16* pV = Vh + (size_t)c * 2048 + 8 * g;   // + kt*64 + dt*32768 + 32*kb

    f32x4 oacc[4] = {};                   // [dim-tile]
    float mrun = -3.0e38f, lrun = 0.f;

    for (int kt = 0; kt < 32; ++kt) {
        const int koff = kt * 4096;
        const int voff = kt * 64;

        // S[key][q]: sacc[T], lane holds rows 16T+4g+r, col q=c
        f32x4 sacc[4] = {};
#pragma unroll
        for (int T = 0; T < 4; ++T)
#pragma unroll
            for (int kk = 0; kk < 2; ++kk) {
                bf16x8 kf = *(const bf16x8*)&pK[koff + T * 1024 + 32 * kk];
                sacc[T] = __builtin_amdgcn_mfma_f32_16x16x32_bf16(kf, qf[kk], sacc[T], 0, 0, 0);
            }

        // row max over 16 local values, then across g-groups (lanes c,c+16,c+32,c+48)
        float t0 = fmaxf(fmaxf(sacc[0][0], sacc[0][1]), fmaxf(sacc[0][2], sacc[0][3]));
        float t1 = fmaxf(fmaxf(sacc[1][0], sacc[1][1]), fmaxf(sacc[1][2], sacc[1][3]));
        float t2 = fmaxf(fmaxf(sacc[2][0], sacc[2][1]), fmaxf(sacc[2][2], sacc[2][3]));
        float t3 = fmaxf(fmaxf(sacc[3][0], sacc[3][1]), fmaxf(sacc[3][2], sacc[3][3]));
        float mx = fmaxf(fmaxf(t0, t1), fmaxf(t2, t3));
        mx = fmaxf(mx, __shfl_xor(mx, 16));
        mx = fmaxf(mx, __shfl_xor(mx, 32));

        // defer-max (exact): only rescale when some row's max grew
        if (__any(mx > mrun)) {
            const float mnew = fmaxf(mrun, mx);
            const float alpha = __expf(mrun - mnew);
            mrun = mnew;
            lrun *= alpha;
#pragma unroll
            for (int dt = 0; dt < 4; ++dt)
#pragma unroll
                for (int r = 0; r < 4; ++r) oacc[dt][r] *= alpha;
        }

        // P = exp(S - m); pack pairs; row-sum
        u32 pw[4][2];                     // [T][pair]: keys (16T+4g+2p, +1)
        float lsum = 0.f;
#pragma unroll
        for (int T = 0; T < 4; ++T) {
            float p0 = __expf(sacc[T][0] - mrun);
            float p1 = __expf(sacc[T][1] - mrun);
            float p2 = __expf(sacc[T][2] - mrun);
            float p3 = __expf(sacc[T][3] - mrun);
            lsum += (p0 + p1) + (p2 + p3);
            pw[T][0] = pack2(p0, p1);
            pw[T][1] = pack2(p2, p3);
        }
        lsum += __shfl_xor(lsum, 16);
        lsum += __shfl_xor(lsum, 32);
        lrun += lsum;

        // PV: O[dim][q] += V^T . P^T over 2 key-blocks of 32; V A-frag = one 16B load
#pragma unroll
        for (int kb = 0; kb < 2; ++kb) {
            u32x4 ww = {pw[2 * kb][0], pw[2 * kb][1], pw[2 * kb + 1][0], pw[2 * kb + 1][1]};
            bf16x8 pf = __builtin_bit_cast(bf16x8, ww);
#pragma unroll
            for (int dt = 0; dt < 4; ++dt) {
                bf16x8 vf = *(const bf16x8*)&pV[voff + dt * 32768 + 32 * kb];
                oacc[dt] = __builtin_amdgcn_mfma_f32_16x16x32_bf16(vf, pf, oacc[dt], 0, 0, 0);
            }
        }
    }

    // epilogue: O[b, s=q, h*64 + dim], dim = 16*dt + 4g + r
    const float inv = 1.0f / lrun;
    const size_t obase = ((size_t)(b * 2048 + q)) * 1024 + h * 64 + 4 * g;
#pragma unroll
    for (int dt = 0; dt < 4; ++dt) {
        u32x2 pr = {pack2(oacc[dt][0] * inv, oacc[dt][1] * inv),
                    pack2(oacc[dt][2] * inv, oacc[dt][3] * inv)};
        *(u32x2*)&O[obase + 16 * dt] = pr;
    }
}

// ---------------------------------------------------------------- launch
extern "C" void kernel_launch(void* const* d_in, const int* in_sizes, int n_in,
                              void* d_out, int out_size, void* d_ws, size_t ws_size,
                              hipStream_t stream) {
    const float* x  = (const float*)d_in[0];
    const float* Wq = (const float*)d_in[1];
    const float* bq = (const float*)d_in[2];
    const float* Wk = (const float*)d_in[3];
    const float* bk = (const float*)d_in[4];
    const float* Wv = (const float*)d_in[5];
    const float* bv = (const float*)d_in[6];
    const float* Wo = (const float*)d_in[7];
    const float* bo = (const float*)d_in[8];
    float* out = (float*)d_out;

    if (ws_size < (size_t)51 * 1024 * 1024) return;

    u16* ws  = (u16*)d_ws;
    u16* xb  = ws;                       // 4096*1024
    u16* wqt = xb  + 4096 * 1024;
    u16* wkt = wqt + 1024 * 1024;
    u16* wvt = wkt + 1024 * 1024;
    u16* wot = wvt + 1024 * 1024;
    u16* Qb  = wot + 1024 * 1024;        // [B,H,2048,64] (pre-scaled 1/8)
    u16* Kb  = Qb + 4194304;             // [B,H,2048,64]
    u16* Vtb = Kb + 4194304;             // [B,H,64,2048] transposed + key-permuted
    u16* Ob  = Vtb + 4194304;            // [4096][1024]

    cast_x_kernel<<<4096, 256, 0, stream>>>((const float4*)x, xb);
    transpose_cast<<<1024, 256, 0, stream>>>(Wq, Wk, Wv, Wo, wqt, wkt, wvt, wot);
    gemm_kernel<0><<<768, 256, 0, stream>>>(xb, wqt, wkt, wvt, bq, bk, bv,
                                            Qb, Kb, Vtb, nullptr);
    attn_kernel<<<1024, 256, 0, stream>>>(Qb, Kb, Vtb, Ob);
    gemm_kernel<1><<<256, 256, 0, stream>>>(Ob, wot, nullptr, nullptr, bo, nullptr, nullptr,
                                            nullptr, nullptr, nullptr, out);
}

// Round 7
// 251.955 us; speedup vs baseline: 1.5621x; 1.5621x over previous
//
#include <hip/hip_runtime.h>
#include <hip/hip_bf16.h>

typedef unsigned short u16;
typedef unsigned int u32;
typedef short bf16x4 __attribute__((ext_vector_type(4)));
typedef short bf16x8 __attribute__((ext_vector_type(8)));
typedef float f32x4 __attribute__((ext_vector_type(4)));
typedef u32 u32x2 __attribute__((ext_vector_type(2)));
typedef u32 u32x4 __attribute__((ext_vector_type(4)));

#define DEVINL __device__ __forceinline__

DEVINL u16 f2bf(float f) {
    u32 u = __builtin_bit_cast(u32, f);
    u32 r = u + 0x7fffu + ((u >> 16) & 1u);   // RNE
    return (u16)(r >> 16);
}

// RNE pack via scalar casts — compiler fuses to v_cvt_pk_bf16_f32 (m240)
DEVINL u32 pack2(float a, float b) {
    u16 lo = __builtin_bit_cast(u16, __float2bfloat16(a));
    u16 hi = __builtin_bit_cast(u16, __float2bfloat16(b));
    return (u32)lo | ((u32)hi << 16);
}

// ---------------------------------------------------------------- cast x -> bf16
__global__ __launch_bounds__(256) void cast_x_kernel(const float4* __restrict__ in,
                                                     u16* __restrict__ outp) {
    int i = blockIdx.x * 256 + threadIdx.x;
    float4 v = in[i];
    ushort4 o;
    o.x = f2bf(v.x); o.y = f2bf(v.y); o.z = f2bf(v.z); o.w = f2bf(v.w);
    *(ushort4*)&outp[(size_t)i * 4] = o;
}

// ------------------------------------------ transpose+cast weights: W[K][N] -> Wt[N][K] bf16
__global__ __launch_bounds__(256) void transpose_cast(
    const float* __restrict__ W0, const float* __restrict__ W1,
    const float* __restrict__ W2, const float* __restrict__ W3,
    u16* __restrict__ T0, u16* __restrict__ T1,
    u16* __restrict__ T2, u16* __restrict__ T3) {
    __shared__ __align__(16) u16 lds[64 * 68];
    int bid = blockIdx.x;
    const float* W; u16* T;
    switch (bid >> 8) {
        case 0:  W = W0; T = T0; break;
        case 1:  W = W1; T = T1; break;
        case 2:  W = W2; T = T2; break;
        default: W = W3; T = T3; break;
    }
    int tile = bid & 255;
    int k0 = (tile >> 4) << 6;
    int n0 = (tile & 15) << 6;
    int t = threadIdx.x;
    int rk = t >> 2;
    int cb = (t & 3) << 4;
#pragma unroll
    for (int j = 0; j < 4; ++j) {
        float4 v = *(const float4*)&W[(size_t)(k0 + rk) * 1024 + n0 + cb + 4 * j];
        ushort4 o;
        o.x = f2bf(v.x); o.y = f2bf(v.y); o.z = f2bf(v.z); o.w = f2bf(v.w);
        *(ushort4*)&lds[rk * 68 + cb + 4 * j] = o;
    }
    __syncthreads();
    int rn = t >> 2;
#pragma unroll
    for (int j2 = 0; j2 < 2; ++j2) {
        u16 tmp[8];
#pragma unroll
        for (int u = 0; u < 8; ++u)
            tmp[u] = lds[(cb + 8 * j2 + u) * 68 + rn];
        *(uint4*)&T[(size_t)(n0 + rn) * 1024 + k0 + cb + 8 * j2] = *(uint4*)tmp;
    }
}

// ---------------------------------------------------------------- GEMM (m97-style 128^2 tile)
// MODE 0: C[4096,3072] = xb @ [Wq|Wk|Wv]^T-stored, +bias; Q (pre-scaled 0.125*log2e), K -> [B,H,S,64];
//         V -> [B,H,64,S'] key-PERMUTED transposed (pos = 32kb+8g+j <-> key = 32kb+(j<4?4g+j:16+4g+j-4))
// MODE 1: C[4096,1024] = Ob @ Wo^T-stored, +bo, write fp32 d_out
template <int MODE>
__global__ __launch_bounds__(256) void gemm_kernel(
    const u16* __restrict__ A,
    const u16* __restrict__ W0t, const u16* __restrict__ W1t, const u16* __restrict__ W2t,
    const float* __restrict__ b0, const float* __restrict__ b1, const float* __restrict__ b2,
    u16* __restrict__ Oq, u16* __restrict__ Ok, u16* __restrict__ Ov,
    float* __restrict__ Fout) {
    constexpr int NB = (MODE == 0) ? 24 : 8;
    const int mb = blockIdx.x / NB, nb = blockIdx.x % NB;
    const int m0 = mb * 128, n0 = nb * 128;
    const int tid = threadIdx.x, lane = tid & 63, w = tid >> 6;
    const int wr = w >> 1, wc = w & 1;
    const int c = lane & 15, g = lane >> 4;

    __shared__ __align__(16) u16 Alds[128 * 64];
    __shared__ __align__(16) u16 Blds[128 * 64];

    const u16* Wt; const float* bias; int ncol0;
    if (MODE == 0) {
        const int tsel = n0 >> 10;
        Wt   = (tsel == 0) ? W0t : ((tsel == 1) ? W1t : W2t);
        bias = (tsel == 0) ? b0  : ((tsel == 1) ? b1  : b2);
        ncol0 = n0 & 1023;
    } else {
        Wt = W0t; bias = b0; ncol0 = n0;
    }

    const u16* Asrc = A  + (size_t)(m0    + 32 * w + (lane >> 3)) * 1024 + (lane & 7) * 8;
    const u16* Bsrc = Wt + (size_t)(ncol0 + 32 * w + (lane >> 3)) * 1024 + (lane & 7) * 8;
    u16* AldsW = &Alds[(32 * w) * 64];
    u16* BldsW = &Blds[(32 * w) * 64];

    f32x4 acc[4][4] = {};

    for (int kt = 0; kt < 16; ++kt) {
        const int k0 = kt * 64;
#pragma unroll
        for (int i = 0; i < 4; ++i) {
            __builtin_amdgcn_global_load_lds(
                (const __attribute__((address_space(1))) void*)(Asrc + k0 + i * 8 * 1024),
                (__attribute__((address_space(3))) void*)(AldsW + i * 8 * 64), 16, 0, 0);
            __builtin_amdgcn_global_load_lds(
                (const __attribute__((address_space(1))) void*)(Bsrc + k0 + i * 8 * 1024),
                (__attribute__((address_space(3))) void*)(BldsW + i * 8 * 64), 16, 0, 0);
        }
        __syncthreads();
#pragma unroll
        for (int kk = 0; kk < 2; ++kk) {
            bf16x8 af[4], bfr[4];
#pragma unroll
            for (int mf = 0; mf < 4; ++mf)
                af[mf] = *(const bf16x8*)&Alds[(c + 16 * mf + 64 * wr) * 64 + 8 * g + 32 * kk];
#pragma unroll
            for (int nf = 0; nf < 4; ++nf)
                bfr[nf] = *(const bf16x8*)&Blds[(c + 16 * nf + 64 * wc) * 64 + 8 * g + 32 * kk];
#pragma unroll
            for (int mf = 0; mf < 4; ++mf)
#pragma unroll
                for (int nf = 0; nf < 4; ++nf)
                    acc[mf][nf] = __builtin_amdgcn_mfma_f32_16x16x32_bf16(
                        af[mf], bfr[nf], acc[mf][nf], 0, 0, 0);
        }
        __syncthreads();
    }

    float biasv[4];
#pragma unroll
    for (int nf = 0; nf < 4; ++nf) biasv[nf] = bias[ncol0 + 64 * wc + 16 * nf + c];

    if (MODE == 0) {
        const int bi = m0 >> 11;
        const int tsel = n0 >> 10;
        if (tsel < 2) {
            u16* Odst = (tsel == 0) ? Oq : Ok;
            // fold 1/sqrt(Dk) * log2(e) into Q (softmax uses exp2)
            const float sc = (tsel == 0) ? 0.18033688011112042f : 1.0f;
#pragma unroll
            for (int nf = 0; nf < 4; ++nf) {
                const int n_in = ncol0 + 64 * wc + 16 * nf + c;
                const int h = n_in >> 6, d = n_in & 63;
                u16* base = Odst + ((size_t)(bi * 16 + h)) * 2048 * 64 + d;
#pragma unroll
                for (int mf = 0; mf < 4; ++mf)
#pragma unroll
                    for (int r = 0; r < 4; ++r) {
                        const int m = m0 + 64 * wr + 16 * mf + 4 * g + r;
                        const int s = m & 2047;
                        base[(size_t)s * 64] = f2bf((acc[mf][nf][r] + biasv[nf]) * sc);
                    }
            }
        } else {
            // V transposed + key-permuted within each 64-key tile:
            // block of 4 keys s..s+3 (s%4==0) stored at pos = (s&~63) + 32*kb + sub
            //   kb = (s>>5)&1, r5 = s&31, sub = (r5<16) ? 2*r5 : 2*(r5-16)+4
#pragma unroll
            for (int nf = 0; nf < 4; ++nf) {
                const int n_in = ncol0 + 64 * wc + 16 * nf + c;
                const int h = n_in >> 6, d = n_in & 63;
                u16* base = Ov + ((size_t)((bi * 16 + h) * 64 + d)) * 2048;
#pragma unroll
                for (int mf = 0; mf < 4; ++mf) {
                    const int s = (m0 & 2047) + 64 * wr + 16 * mf + 4 * g;
                    const int r5 = s & 31;
                    const int pos = (s & ~63) + 32 * ((s >> 5) & 1)
                                  + ((r5 < 16) ? (2 * r5) : (2 * (r5 - 16) + 4));
                    u32x2 pr = {pack2(acc[mf][nf][0] + biasv[nf], acc[mf][nf][1] + biasv[nf]),
                                pack2(acc[mf][nf][2] + biasv[nf], acc[mf][nf][3] + biasv[nf])};
                    *(u32x2*)&base[pos] = pr;
                }
            }
        }
    } else {
#pragma unroll
        for (int mf = 0; mf < 4; ++mf)
#pragma unroll
            for (int r = 0; r < 4; ++r) {
                const int m = m0 + 64 * wr + 16 * mf + 4 * g + r;
                float* rowp = Fout + (size_t)m * 1024 + n0 + 64 * wc;
#pragma unroll
                for (int nf = 0; nf < 4; ++nf)
                    rowp[16 * nf + c] = acc[mf][nf][r] + biasv[nf];
            }
    }
}

// ---------------------------------------------------------------- flash attention
// LDS-staged via global_load_lds DMA into a conflict-free subtile layout.
// LDS chunk layout (per 64-key tile, 8KB = 512 x 16B chunks):
//   chunk = st*64 + 4*c + g  (st = 2T+kk for K / 2dt+kb for V; c=0..15, g=0..3)
//   K chunk content = K[16T+c][32kk+8g .. +7];  V chunk = Vp[16dt+c][kt*64+32kb+8g .. +7]
// => every wave MFMA operand read: 64 lanes hit 64 CONTIGUOUS 16B chunks (zero conflicts).
// Staging: wave w DMAs subtiles st=2w,2w+1 (LDS dest linear by lane; per-lane global
// source = chunk source — the "pre-swizzled source" pattern, m173).
// grid: 1024 = B x H x (2048/64); 4 waves x 16q; Q pre-scaled 0.125*log2e, exp2 softmax.
__global__ __launch_bounds__(256) void attn_kernel(
    const u16* __restrict__ Q, const u16* __restrict__ K, const u16* __restrict__ Vp,
    u16* __restrict__ O) {
    const int bid0 = blockIdx.x;
    const int bid = (bid0 & 7) * 128 + (bid0 >> 3);   // XCD-chunked swizzle (1024 % 8 == 0)
    const int qb = bid & 31, h = (bid >> 5) & 15, b = bid >> 9;
    const int tid = threadIdx.x, lane = tid & 63, w = tid >> 6;
    const int c = lane & 15, g = lane >> 4;

    __shared__ __align__(16) u16 KL[2][4096];   // 8KB per buffer
    __shared__ __align__(16) u16 VL[2][4096];

    const size_t hoff = ((size_t)(b * 16 + h)) * 2048 * 64;
    const u16* Qh = Q + hoff;
    const u16* Kh = K + hoff;
    const u16* Vh = Vp + hoff;      // [64 dims][2048 key-positions (permuted per 64)]

    const int q = qb * 64 + w * 16 + c;   // this lane's q-row
    bf16x8 qf[2];
#pragma unroll
    for (int kk = 0; kk < 2; ++kk)
        qf[kk] = *(const bf16x8*)&Qh[(size_t)q * 64 + 8 * g + 32 * kk];

    // per-lane DMA source bases (chunk = 64*(2w+j) + lane; c_s = lane>>2, g_s = lane&3)
    const u16* kSrc = Kh + (size_t)(16 * w + (lane >> 2)) * 64 + 8 * (lane & 3);
    const u16* vSrc = Vh + (size_t)(16 * w + (lane >> 2)) * 2048 + 8 * (lane & 3);
    // wave-uniform LDS dest bases (u16 index): subtile st occupies [st*512, st*512+512)
    const int kdBase = (2 * w) * 512;

#define STAGE(bi_, kt_) do {                                                              \
        const u16* ks_ = kSrc + (kt_) * 4096;                                             \
        const u16* vs_ = vSrc + (kt_) * 64;                                               \
        __builtin_amdgcn_global_load_lds(                                                 \
            (const __attribute__((address_space(1))) void*)(ks_),                         \
            (__attribute__((address_space(3))) void*)(&KL[bi_][kdBase]), 16, 0, 0);       \
        __builtin_amdgcn_global_load_lds(                                                 \
            (const __attribute__((address_space(1))) void*)(ks_ + 32),                    \
            (__attribute__((address_space(3))) void*)(&KL[bi_][kdBase + 512]), 16, 0, 0); \
        __builtin_amdgcn_global_load_lds(                                                 \
            (const __attribute__((address_space(1))) void*)(vs_),                         \
            (__attribute__((address_space(3))) void*)(&VL[bi_][kdBase]), 16, 0, 0);       \
        __builtin_amdgcn_global_load_lds(                                                 \
            (const __attribute__((address_space(1))) void*)(vs_ + 32),                    \
            (__attribute__((address_space(3))) void*)(&VL[bi_][kdBase + 512]), 16, 0, 0); \
    } while (0)

    f32x4 oacc[4] = {};                   // [dim-tile]
    float mrun = -3.0e38f, lrun = 0.f;

    STAGE(0, 0);
    __syncthreads();

    for (int kt = 0; kt < 32; ++kt) {
        const int cur = kt & 1, nxt = cur ^ 1;
        if (kt < 31) STAGE(nxt, kt + 1);   // DMA next tile; drains at the end barrier

        const u16* Kb0 = &KL[cur][0];
        const u16* Vb0 = &VL[cur][0];

        // S[key][q]: sacc[T], lane holds rows 16T+4g+r, col q=c (log2-domain scores)
        f32x4 sacc[4] = {};
#pragma unroll
        for (int T = 0; T < 4; ++T)
#pragma unroll
            for (int kk = 0; kk < 2; ++kk) {
                bf16x8 kf = *(const bf16x8*)&Kb0[(2 * T + kk) * 512 + 32 * c + 8 * g];
                sacc[T] = __builtin_amdgcn_mfma_f32_16x16x32_bf16(kf, qf[kk], sacc[T], 0, 0, 0);
            }

        // row max over 16 local values, then across g-groups (lanes c,c+16,c+32,c+48)
        float t0 = fmaxf(fmaxf(sacc[0][0], sacc[0][1]), fmaxf(sacc[0][2], sacc[0][3]));
        float t1 = fmaxf(fmaxf(sacc[1][0], sacc[1][1]), fmaxf(sacc[1][2], sacc[1][3]));
        float t2 = fmaxf(fmaxf(sacc[2][0], sacc[2][1]), fmaxf(sacc[2][2], sacc[2][3]));
        float t3 = fmaxf(fmaxf(sacc[3][0], sacc[3][1]), fmaxf(sacc[3][2], sacc[3][3]));
        float mx = fmaxf(fmaxf(t0, t1), fmaxf(t2, t3));
        mx = fmaxf(mx, __shfl_xor(mx, 16));
        mx = fmaxf(mx, __shfl_xor(mx, 32));

        // defer-max (exact): only rescale when some row's max grew
        if (__any(mx > mrun)) {
            const float mnew = fmaxf(mrun, mx);
            const float alpha = exp2f(mrun - mnew);
            mrun = mnew;
            lrun *= alpha;
#pragma unroll
            for (int dt = 0; dt < 4; ++dt)
#pragma unroll
                for (int r = 0; r < 4; ++r) oacc[dt][r] *= alpha;
        }

        // P = exp2(S - m); pack pairs; row-sum
        u32 pw[4][2];                     // [T][pair]: keys (16T+4g+2p, +1)
        float lsum = 0.f;
#pragma unroll
        for (int T = 0; T < 4; ++T) {
            float p0 = exp2f(sacc[T][0] - mrun);
            float p1 = exp2f(sacc[T][1] - mrun);
            float p2 = exp2f(sacc[T][2] - mrun);
            float p3 = exp2f(sacc[T][3] - mrun);
            lsum += (p0 + p1) + (p2 + p3);
            pw[T][0] = pack2(p0, p1);
            pw[T][1] = pack2(p2, p3);
        }
        lsum += __shfl_xor(lsum, 16);
        lsum += __shfl_xor(lsum, 32);
        lrun += lsum;

        // PV: O[dim][q] += V^T . P^T over 2 key-blocks of 32, claimed-map kappa
        //   (V stored key-permuted so the A-frag is one conflict-free b128 read)
#pragma unroll
        for (int kb = 0; kb < 2; ++kb) {
            u32x4 ww = {pw[2 * kb][0], pw[2 * kb][1], pw[2 * kb + 1][0], pw[2 * kb + 1][1]};
            bf16x8 pf = __builtin_bit_cast(bf16x8, ww);
#pragma unroll
            for (int dt = 0; dt < 4; ++dt) {
                bf16x8 vf = *(const bf16x8*)&Vb0[(2 * dt + kb) * 512 + 32 * c + 8 * g];
                oacc[dt] = __builtin_amdgcn_mfma_f32_16x16x32_bf16(vf, pf, oacc[dt], 0, 0, 0);
            }
        }

        __syncthreads();   // compiler drains vmcnt/lgkm: next buffer ready, cur free
    }
#undef STAGE

    // epilogue: O[b, s=q, h*64 + dim], dim = 16*dt + 4g + r
    const float inv = 1.0f / lrun;
    const size_t obase = ((size_t)(b * 2048 + q)) * 1024 + h * 64 + 4 * g;
#pragma unroll
    for (int dt = 0; dt < 4; ++dt) {
        u32x2 pr = {pack2(oacc[dt][0] * inv, oacc[dt][1] * inv),
                    pack2(oacc[dt][2] * inv, oacc[dt][3] * inv)};
        *(u32x2*)&O[obase + 16 * dt] = pr;
    }
}

// ---------------------------------------------------------------- launch
extern "C" void kernel_launch(void* const* d_in, const int* in_sizes, int n_in,
                              void* d_out, int out_size, void* d_ws, size_t ws_size,
                              hipStream_t stream) {
    const float* x  = (const float*)d_in[0];
    const float* Wq = (const float*)d_in[1];
    const float* bq = (const float*)d_in[2];
    const float* Wk = (const float*)d_in[3];
    const float* bk = (const float*)d_in[4];
    const float* Wv = (const float*)d_in[5];
    const float* bv = (const float*)d_in[6];
    const float* Wo = (const float*)d_in[7];
    const float* bo = (const float*)d_in[8];
    float* out = (float*)d_out;

    if (ws_size < (size_t)51 * 1024 * 1024) return;

    u16* ws  = (u16*)d_ws;
    u16* xb  = ws;                       // 4096*1024
    u16* wqt = xb  + 4096 * 1024;
    u16* wkt = wqt + 1024 * 1024;
    u16* wvt = wkt + 1024 * 1024;
    u16* wot = wvt + 1024 * 1024;
    u16* Qb  = wot + 1024 * 1024;        // [B,H,2048,64] (pre-scaled 0.125*log2e)
    u16* Kb  = Qb + 4194304;             // [B,H,2048,64]
    u16* Vtb = Kb + 4194304;             // [B,H,64,2048] transposed + key-permuted
    u16* Ob  = Vtb + 4194304;            // [4096][1024]

    cast_x_kernel<<<4096, 256, 0, stream>>>((const float4*)x, xb);
    transpose_cast<<<1024, 256, 0, stream>>>(Wq, Wk, Wv, Wo, wqt, wkt, wvt, wot);
    gemm_kernel<0><<<768, 256, 0, stream>>>(xb, wqt, wkt, wvt, bq, bk, bv,
                                            Qb, Kb, Vtb, nullptr);
    attn_kernel<<<1024, 256, 0, stream>>>(Qb, Kb, Vtb, Ob);
    gemm_kernel<1><<<256, 256, 0, stream>>>(Ob, wot, nullptr, nullptr, bo, nullptr, nullptr,
                                            nullptr, nullptr, nullptr, out);
}

// Round 8
// 232.352 us; speedup vs baseline: 1.6939x; 1.0844x over previous
//
#include <hip/hip_runtime.h>
#include <hip/hip_bf16.h>

typedef unsigned short u16;
typedef unsigned int u32;
typedef short bf16x4 __attribute__((ext_vector_type(4)));
typedef short bf16x8 __attribute__((ext_vector_type(8)));
typedef float f32x4 __attribute__((ext_vector_type(4)));
typedef u32 u32x2 __attribute__((ext_vector_type(2)));
typedef u32 u32x4 __attribute__((ext_vector_type(4)));

#define DEVINL __device__ __forceinline__

DEVINL u16 f2bf(float f) {
    u32 u = __builtin_bit_cast(u32, f);
    u32 r = u + 0x7fffu + ((u >> 16) & 1u);   // RNE
    return (u16)(r >> 16);
}

// RNE pack via scalar casts — compiler fuses to v_cvt_pk_bf16_f32 (m240)
DEVINL u32 pack2(float a, float b) {
    u16 lo = __builtin_bit_cast(u16, __float2bfloat16(a));
    u16 hi = __builtin_bit_cast(u16, __float2bfloat16(b));
    return (u32)lo | ((u32)hi << 16);
}

// ---------------------------------------------------------------- cast x -> bf16
__global__ __launch_bounds__(256) void cast_x_kernel(const float4* __restrict__ in,
                                                     u16* __restrict__ outp) {
    int i = blockIdx.x * 256 + threadIdx.x;
    float4 v = in[i];
    ushort4 o;
    o.x = f2bf(v.x); o.y = f2bf(v.y); o.z = f2bf(v.z); o.w = f2bf(v.w);
    *(ushort4*)&outp[(size_t)i * 4] = o;
}

// ------------------------------------------ transpose+cast weights: W[K][N] -> Wt[N][K] bf16
__global__ __launch_bounds__(256) void transpose_cast(
    const float* __restrict__ W0, const float* __restrict__ W1,
    const float* __restrict__ W2, const float* __restrict__ W3,
    u16* __restrict__ T0, u16* __restrict__ T1,
    u16* __restrict__ T2, u16* __restrict__ T3) {
    __shared__ __align__(16) u16 lds[64 * 68];
    int bid = blockIdx.x;
    const float* W; u16* T;
    switch (bid >> 8) {
        case 0:  W = W0; T = T0; break;
        case 1:  W = W1; T = T1; break;
        case 2:  W = W2; T = T2; break;
        default: W = W3; T = T3; break;
    }
    int tile = bid & 255;
    int k0 = (tile >> 4) << 6;
    int n0 = (tile & 15) << 6;
    int t = threadIdx.x;
    int rk = t >> 2;
    int cb = (t & 3) << 4;
#pragma unroll
    for (int j = 0; j < 4; ++j) {
        float4 v = *(const float4*)&W[(size_t)(k0 + rk) * 1024 + n0 + cb + 4 * j];
        ushort4 o;
        o.x = f2bf(v.x); o.y = f2bf(v.y); o.z = f2bf(v.z); o.w = f2bf(v.w);
        *(ushort4*)&lds[rk * 68 + cb + 4 * j] = o;
    }
    __syncthreads();
    int rn = t >> 2;
#pragma unroll
    for (int j2 = 0; j2 < 2; ++j2) {
        u16 tmp[8];
#pragma unroll
        for (int u = 0; u < 8; ++u)
            tmp[u] = lds[(cb + 8 * j2 + u) * 68 + rn];
        *(uint4*)&T[(size_t)(n0 + rn) * 1024 + k0 + cb + 8 * j2] = *(uint4*)tmp;
    }
}

// ---------------------------------------------------------------- GEMM (m97-style 128^2 tile)
// MODE 0: C[4096,3072] = xb @ [Wq|Wk|Wv]^T-stored, +bias; Q (pre-scaled 1/8), K -> [B,H,S,64];
//         V -> [B,H,64,S'] key-PERMUTED transposed (pos = 32kb+8g+j <-> key = 32kb+(j<4?4g+j:16+4g+j-4))
// MODE 1: C[4096,1024] = Ob @ Wo^T-stored, +bo, write fp32 d_out
template <int MODE>
__global__ __launch_bounds__(256) void gemm_kernel(
    const u16* __restrict__ A,
    const u16* __restrict__ W0t, const u16* __restrict__ W1t, const u16* __restrict__ W2t,
    const float* __restrict__ b0, const float* __restrict__ b1, const float* __restrict__ b2,
    u16* __restrict__ Oq, u16* __restrict__ Ok, u16* __restrict__ Ov,
    float* __restrict__ Fout) {
    constexpr int NB = (MODE == 0) ? 24 : 8;
    const int mb = blockIdx.x / NB, nb = blockIdx.x % NB;
    const int m0 = mb * 128, n0 = nb * 128;
    const int tid = threadIdx.x, lane = tid & 63, w = tid >> 6;
    const int wr = w >> 1, wc = w & 1;
    const int c = lane & 15, g = lane >> 4;

    __shared__ __align__(16) u16 Alds[128 * 64];
    __shared__ __align__(16) u16 Blds[128 * 64];

    const u16* Wt; const float* bias; int ncol0;
    if (MODE == 0) {
        const int tsel = n0 >> 10;
        Wt   = (tsel == 0) ? W0t : ((tsel == 1) ? W1t : W2t);
        bias = (tsel == 0) ? b0  : ((tsel == 1) ? b1  : b2);
        ncol0 = n0 & 1023;
    } else {
        Wt = W0t; bias = b0; ncol0 = n0;
    }

    const u16* Asrc = A  + (size_t)(m0    + 32 * w + (lane >> 3)) * 1024 + (lane & 7) * 8;
    const u16* Bsrc = Wt + (size_t)(ncol0 + 32 * w + (lane >> 3)) * 1024 + (lane & 7) * 8;
    u16* AldsW = &Alds[(32 * w) * 64];
    u16* BldsW = &Blds[(32 * w) * 64];

    f32x4 acc[4][4] = {};

    for (int kt = 0; kt < 16; ++kt) {
        const int k0 = kt * 64;
#pragma unroll
        for (int i = 0; i < 4; ++i) {
            __builtin_amdgcn_global_load_lds(
                (const __attribute__((address_space(1))) void*)(Asrc + k0 + i * 8 * 1024),
                (__attribute__((address_space(3))) void*)(AldsW + i * 8 * 64), 16, 0, 0);
            __builtin_amdgcn_global_load_lds(
                (const __attribute__((address_space(1))) void*)(Bsrc + k0 + i * 8 * 1024),
                (__attribute__((address_space(3))) void*)(BldsW + i * 8 * 64), 16, 0, 0);
        }
        __syncthreads();
#pragma unroll
        for (int kk = 0; kk < 2; ++kk) {
            bf16x8 af[4], bfr[4];
#pragma unroll
            for (int mf = 0; mf < 4; ++mf)
                af[mf] = *(const bf16x8*)&Alds[(c + 16 * mf + 64 * wr) * 64 + 8 * g + 32 * kk];
#pragma unroll
            for (int nf = 0; nf < 4; ++nf)
                bfr[nf] = *(const bf16x8*)&Blds[(c + 16 * nf + 64 * wc) * 64 + 8 * g + 32 * kk];
#pragma unroll
            for (int mf = 0; mf < 4; ++mf)
#pragma unroll
                for (int nf = 0; nf < 4; ++nf)
                    acc[mf][nf] = __builtin_amdgcn_mfma_f32_16x16x32_bf16(
                        af[mf], bfr[nf], acc[mf][nf], 0, 0, 0);
        }
        __syncthreads();
    }

    float biasv[4];
#pragma unroll
    for (int nf = 0; nf < 4; ++nf) biasv[nf] = bias[ncol0 + 64 * wc + 16 * nf + c];

    if (MODE == 0) {
        const int bi = m0 >> 11;
        const int tsel = n0 >> 10;
        if (tsel < 2) {
            u16* Odst = (tsel == 0) ? Oq : Ok;
            const float sc = (tsel == 0) ? 0.125f : 1.0f;   // fold 1/sqrt(Dk) into Q
#pragma unroll
            for (int nf = 0; nf < 4; ++nf) {
                const int n_in = ncol0 + 64 * wc + 16 * nf + c;
                const int h = n_in >> 6, d = n_in & 63;
                u16* base = Odst + ((size_t)(bi * 16 + h)) * 2048 * 64 + d;
#pragma unroll
                for (int mf = 0; mf < 4; ++mf)
#pragma unroll
                    for (int r = 0; r < 4; ++r) {
                        const int m = m0 + 64 * wr + 16 * mf + 4 * g + r;
                        const int s = m & 2047;
                        base[(size_t)s * 64] = f2bf((acc[mf][nf][r] + biasv[nf]) * sc);
                    }
            }
        } else {
            // V transposed + key-permuted within each 64-key tile:
            // block of 4 keys s..s+3 (s%4==0) stored at pos = (s&~63) + 32*kb + sub
            //   kb = (s>>5)&1, r5 = s&31, sub = (r5<16) ? 2*r5 : 2*(r5-16)+4
#pragma unroll
            for (int nf = 0; nf < 4; ++nf) {
                const int n_in = ncol0 + 64 * wc + 16 * nf + c;
                const int h = n_in >> 6, d = n_in & 63;
                u16* base = Ov + ((size_t)((bi * 16 + h) * 64 + d)) * 2048;
#pragma unroll
                for (int mf = 0; mf < 4; ++mf) {
                    const int s = (m0 & 2047) + 64 * wr + 16 * mf + 4 * g;
                    const int r5 = s & 31;
                    const int pos = (s & ~63) + 32 * ((s >> 5) & 1)
                                  + ((r5 < 16) ? (2 * r5) : (2 * (r5 - 16) + 4));
                    u32x2 pr = {pack2(acc[mf][nf][0] + biasv[nf], acc[mf][nf][1] + biasv[nf]),
                                pack2(acc[mf][nf][2] + biasv[nf], acc[mf][nf][3] + biasv[nf])};
                    *(u32x2*)&base[pos] = pr;
                }
            }
        }
    } else {
#pragma unroll
        for (int mf = 0; mf < 4; ++mf)
#pragma unroll
            for (int r = 0; r < 4; ++r) {
                const int m = m0 + 64 * wr + 16 * mf + 4 * g + r;
                float* rowp = Fout + (size_t)m * 1024 + n0 + 64 * wc;
#pragma unroll
                for (int nf = 0; nf < 4; ++nf)
                    rowp[16 * nf + c] = acc[mf][nf][r] + biasv[nf];
            }
    }
}

// ---------------------------------------------------------------- flash attention
// 8 waves x 32 q/wave = 256 q per block; grid 256 = B x H x (2048/256).
// Minimal staging: each block sweeps 2048 keys ONCE for 256 q (4x less aggregate
// staging than R7); each K/V LDS fragment read feeds TWO MFMAs (2:1 density).
// LDS subtile layout (per 64-key tile, 16 subtiles of 1024B):
//   K subtile st=2T+kk: chunk(lane)=c*4+g holds K[16T+c][32kk+8g..+7]
//   V subtile st=2dt+kb: chunk holds Vp[16dt+c][kt*64+32kb+8g..+7]
// Staged by wave w = st via one global_load_lds(16B) each for K and V (DMA, zero
// staging VALU; LDS dest linear by lane, per-lane source = chunk content, m173).
// Q pre-scaled 1/8; softmax uses native __expf (v_mul+v_exp — exp2f ocml regressed R7).
__global__ __launch_bounds__(512) void attn_kernel(
    const u16* __restrict__ Q, const u16* __restrict__ K, const u16* __restrict__ Vp,
    u16* __restrict__ O) {
    const int bid0 = blockIdx.x;
    const int bid = (bid0 & 7) * 32 + (bid0 >> 3);   // XCD-chunked swizzle (256 % 8 == 0)
    const int qb = bid & 7, h = (bid >> 3) & 15, b = bid >> 7;
    const int tid = threadIdx.x, lane = tid & 63, w = tid >> 6;   // w = 0..7
    const int c = lane & 15, g = lane >> 4;

    __shared__ __align__(16) u16 KL[2][4096];   // 8KB per buffer (16 subtiles x 512 u16 / 2 arrays)
    __shared__ __align__(16) u16 VL[2][4096];

    const size_t hoff = ((size_t)(b * 16 + h)) * 2048 * 64;
    const u16* Qh = Q + hoff;
    const u16* Kh = K + hoff;
    const u16* Vh = Vp + hoff;      // [64 dims][2048 key-positions (permuted per 64)]

    const int q0 = qb * 256 + w * 32;     // wave's q base (2 q-tiles of 16)
    bf16x8 qf[2][2];
#pragma unroll
    for (int u = 0; u < 2; ++u)
#pragma unroll
        for (int kk = 0; kk < 2; ++kk)
            qf[u][kk] = *(const bf16x8*)&Qh[(size_t)(q0 + 16 * u + c) * 64 + 8 * g + 32 * kk];

    // this wave stages subtile st = w for both K (T=w>>1, kk=w&1) and V (dt=w>>1, kb=w&1)
    const u16* kSrc = Kh + (size_t)(16 * (w >> 1) + (lane >> 2)) * 64 + 32 * (w & 1) + 8 * (lane & 3);
    const u16* vSrc = Vh + (size_t)(16 * (w >> 1) + (lane >> 2)) * 2048 + 32 * (w & 1) + 8 * (lane & 3);
    const int dBase = w * 512;            // wave-uniform LDS dest (u16 idx)

#define STAGE(bi_, kt_) do {                                                              \
        __builtin_amdgcn_global_load_lds(                                                 \
            (const __attribute__((address_space(1))) void*)(kSrc + (kt_) * 4096),         \
            (__attribute__((address_space(3))) void*)(&KL[bi_][dBase]), 16, 0, 0);        \
        __builtin_amdgcn_global_load_lds(                                                 \
            (const __attribute__((address_space(1))) void*)(vSrc + (kt_) * 64),           \
            (__attribute__((address_space(3))) void*)(&VL[bi_][dBase]), 16, 0, 0);        \
    } while (0)

    f32x4 oacc[2][4] = {};                // [q-tile][dim-tile]
    float mrun[2] = {-3.0e38f, -3.0e38f}, lrun[2] = {0.f, 0.f};

    STAGE(0, 0);
    __syncthreads();

    for (int kt = 0; kt < 32; ++kt) {
        const int cur = kt & 1, nxt = cur ^ 1;
        if (kt < 31) STAGE(nxt, kt + 1);   // DMA next tile; drains at the end barrier

        const u16* Kb0 = &KL[cur][0];
        const u16* Vb0 = &VL[cur][0];

        // S[key][q]: sacc[u][T], lane holds rows 16T+4g+r, col q=c; each kf feeds 2 MFMAs
        f32x4 sacc[2][4] = {};
#pragma unroll
        for (int T = 0; T < 4; ++T)
#pragma unroll
            for (int kk = 0; kk < 2; ++kk) {
                bf16x8 kf = *(const bf16x8*)&Kb0[(2 * T + kk) * 512 + 32 * c + 8 * g];
                sacc[0][T] = __builtin_amdgcn_mfma_f32_16x16x32_bf16(kf, qf[0][kk], sacc[0][T], 0, 0, 0);
                sacc[1][T] = __builtin_amdgcn_mfma_f32_16x16x32_bf16(kf, qf[1][kk], sacc[1][T], 0, 0, 0);
            }

        // online softmax per q-tile (reduce across g-groups: lanes c,c+16,c+32,c+48)
        u32 pw[2][4][2];
#pragma unroll
        for (int u = 0; u < 2; ++u) {
            float t0 = fmaxf(fmaxf(sacc[u][0][0], sacc[u][0][1]), fmaxf(sacc[u][0][2], sacc[u][0][3]));
            float t1 = fmaxf(fmaxf(sacc[u][1][0], sacc[u][1][1]), fmaxf(sacc[u][1][2], sacc[u][1][3]));
            float t2 = fmaxf(fmaxf(sacc[u][2][0], sacc[u][2][1]), fmaxf(sacc[u][2][2], sacc[u][2][3]));
            float t3 = fmaxf(fmaxf(sacc[u][3][0], sacc[u][3][1]), fmaxf(sacc[u][3][2], sacc[u][3][3]));
            float mx = fmaxf(fmaxf(t0, t1), fmaxf(t2, t3));
            mx = fmaxf(mx, __shfl_xor(mx, 16));
            mx = fmaxf(mx, __shfl_xor(mx, 32));

            // defer-max (exact): only rescale when some row's max grew
            if (__any(mx > mrun[u])) {
                const float mnew = fmaxf(mrun[u], mx);
                const float alpha = __expf(mrun[u] - mnew);
                mrun[u] = mnew;
                lrun[u] *= alpha;
#pragma unroll
                for (int dt = 0; dt < 4; ++dt)
#pragma unroll
                    for (int r = 0; r < 4; ++r) oacc[u][dt][r] *= alpha;
            }

            float lsum = 0.f;
#pragma unroll
            for (int T = 0; T < 4; ++T) {
                float p0 = __expf(sacc[u][T][0] - mrun[u]);
                float p1 = __expf(sacc[u][T][1] - mrun[u]);
                float p2 = __expf(sacc[u][T][2] - mrun[u]);
                float p3 = __expf(sacc[u][T][3] - mrun[u]);
                lsum += (p0 + p1) + (p2 + p3);
                pw[u][T][0] = pack2(p0, p1);
                pw[u][T][1] = pack2(p2, p3);
            }
            lsum += __shfl_xor(lsum, 16);
            lsum += __shfl_xor(lsum, 32);
            lrun[u] += lsum;
        }

        // PV: O[dim][q] += V^T . P^T over 2 key-blocks of 32, claimed-map kappa;
        // each vf read feeds 2 MFMAs (q-tiles)
#pragma unroll
        for (int kb = 0; kb < 2; ++kb) {
            u32x4 w0 = {pw[0][2 * kb][0], pw[0][2 * kb][1], pw[0][2 * kb + 1][0], pw[0][2 * kb + 1][1]};
            u32x4 w1 = {pw[1][2 * kb][0], pw[1][2 * kb][1], pw[1][2 * kb + 1][0], pw[1][2 * kb + 1][1]};
            bf16x8 pf0 = __builtin_bit_cast(bf16x8, w0);
            bf16x8 pf1 = __builtin_bit_cast(bf16x8, w1);
#pragma unroll
            for (int dt = 0; dt < 4; ++dt) {
                bf16x8 vf = *(const bf16x8*)&Vb0[(2 * dt + kb) * 512 + 32 * c + 8 * g];
                oacc[0][dt] = __builtin_amdgcn_mfma_f32_16x16x32_bf16(vf, pf0, oacc[0][dt], 0, 0, 0);
                oacc[1][dt] = __builtin_amdgcn_mfma_f32_16x16x32_bf16(vf, pf1, oacc[1][dt], 0, 0, 0);
            }
        }

        __syncthreads();   // drains vmcnt/lgkm: next buffer ready, cur free
    }
#undef STAGE

    // epilogue: O[b, s=q, h*64 + dim], dim = 16*dt + 4g + r
#pragma unroll
    for (int u = 0; u < 2; ++u) {
        const float inv = 1.0f / lrun[u];
        const size_t obase = ((size_t)(b * 2048 + q0 + 16 * u + c)) * 1024 + h * 64 + 4 * g;
#pragma unroll
        for (int dt = 0; dt < 4; ++dt) {
            u32x2 pr = {pack2(oacc[u][dt][0] * inv, oacc[u][dt][1] * inv),
                        pack2(oacc[u][dt][2] * inv, oacc[u][dt][3] * inv)};
            *(u32x2*)&O[obase + 16 * dt] = pr;
        }
    }
}

// ---------------------------------------------------------------- launch
extern "C" void kernel_launch(void* const* d_in, const int* in_sizes, int n_in,
                              void* d_out, int out_size, void* d_ws, size_t ws_size,
                              hipStream_t stream) {
    const float* x  = (const float*)d_in[0];
    const float* Wq = (const float*)d_in[1];
    const float* bq = (const float*)d_in[2];
    const float* Wk = (const float*)d_in[3];
    const float* bk = (const float*)d_in[4];
    const float* Wv = (const float*)d_in[5];
    const float* bv = (const float*)d_in[6];
    const float* Wo = (const float*)d_in[7];
    const float* bo = (const float*)d_in[8];
    float* out = (float*)d_out;

    if (ws_size < (size_t)51 * 1024 * 1024) return;

    u16* ws  = (u16*)d_ws;
    u16* xb  = ws;                       // 4096*1024
    u16* wqt = xb  + 4096 * 1024;
    u16* wkt = wqt + 1024 * 1024;
    u16* wvt = wkt + 1024 * 1024;
    u16* wot = wvt + 1024 * 1024;
    u16* Qb  = wot + 1024 * 1024;        // [B,H,2048,64] (pre-scaled 1/8)
    u16* Kb  = Qb + 4194304;             // [B,H,2048,64]
    u16* Vtb = Kb + 4194304;             // [B,H,64,2048] transposed + key-permuted
    u16* Ob  = Vtb + 4194304;            // [4096][1024]

    cast_x_kernel<<<4096, 256, 0, stream>>>((const float4*)x, xb);
    transpose_cast<<<1024, 256, 0, stream>>>(Wq, Wk, Wv, Wo, wqt, wkt, wvt, wot);
    gemm_kernel<0><<<768, 256, 0, stream>>>(xb, wqt, wkt, wvt, bq, bk, bv,
                                            Qb, Kb, Vtb, nullptr);
    attn_kernel<<<256, 512, 0, stream>>>(Qb, Kb, Vtb, Ob);
    gemm_kernel<1><<<256, 256, 0, stream>>>(Ob, wot, nullptr, nullptr, bo, nullptr, nullptr,
                                            nullptr, nullptr, nullptr, out);
}